// Round 18
// baseline (371.603 us; speedup 1.0000x reference)
//
#include <hip/hip_runtime.h>

#define SS 512
#define DD 768
#define TT 64

typedef __attribute__((ext_vector_type(2))) float f32x2;

__device__ __forceinline__ f32x2 vmax2(f32x2 a, f32x2 b) {
    return __builtin_elementwise_max(a, b);
}

// ---------------------------------------------------------------------------
// Kernel 0: transpose W[64][768] -> WT[768][64] (write-coalesced, one-shot).
// ---------------------------------------------------------------------------
__global__ __launch_bounds__(256) void transpose_w(
    const float* __restrict__ W, float* __restrict__ WT)
{
    const int idx = blockIdx.x * 256 + threadIdx.x;   // 0..49151
    WT[idx] = W[(idx & 63) * DD + (idx >> 6)];
}

// ---------------------------------------------------------------------------
// Kernel 1: emissions GEMM, LANE = OUTPUT TAG. No LDS, no barriers.
// Each wave computes 16 rows x 64 tags. Per k: one coalesced 256B load of
// WT[k][lane] (L2-hot, shared by all waves) + scalar (wave-uniform) X loads
// feeding v_fma with SGPR operand. em bit-identical to previous rounds:
// sequential k=0..767 fmaf chain, bias added once at the end.
// 2048 waves = 8/CU -> FMA-issue-bound ~= 20.5 us VALU roofline.
// ---------------------------------------------------------------------------
__global__ __launch_bounds__(256) void emis_gemm(
    const float* __restrict__ X, const float* __restrict__ WT,
    const float* __restrict__ bias, float* __restrict__ em)
{
    const int wave = blockIdx.x * 4 + (threadIdx.x >> 6);   // 0..2047
    const int lane = threadIdx.x & 63;
    const int row0 = wave * 16;                              // 16 rows/wave

    float acc[16];
#pragma unroll
    for (int r = 0; r < 16; r++) acc[r] = 0.f;

    // 8-deep register prefetch of the WT stream
    float wt[8];
#pragma unroll
    for (int j = 0; j < 8; j++) wt[j] = WT[j * TT + lane];

    for (int k = 0; k < DD; k += 8) {
        float w0 = wt[0], w1 = wt[1], w2 = wt[2], w3 = wt[3];
        float w4 = wt[4], w5 = wt[5], w6 = wt[6], w7 = wt[7];
        if (k + 8 < DD) {
#pragma unroll
            for (int j = 0; j < 8; j++) wt[j] = WT[(k + 8 + j) * TT + lane];
        }
#pragma unroll
        for (int r = 0; r < 16; r++) {
            // wave-uniform addresses -> scalar loads
            const float4 x0 = *(const float4*)&X[(size_t)(row0 + r) * DD + k];
            const float4 x1 = *(const float4*)&X[(size_t)(row0 + r) * DD + k + 4];
            float a = acc[r];
            a = fmaf(x0.x, w0, a);  a = fmaf(x0.y, w1, a);
            a = fmaf(x0.z, w2, a);  a = fmaf(x0.w, w3, a);
            a = fmaf(x1.x, w4, a);  a = fmaf(x1.y, w5, a);
            a = fmaf(x1.z, w6, a);  a = fmaf(x1.w, w7, a);
            acc[r] = a;
        }
    }

    const float bv = bias[lane];
#pragma unroll
    for (int r = 0; r < 16; r++)
        em[(size_t)(row0 + r) * TT + lane] = acc[r] + bv;
}

// ---------------------------------------------------------------------------
// Kernel 2: Viterbi forward, VALUE ONLY (R10 code, 112 us measured).
// One wave per batch, waves_per_eu(1,1) keeps tpk[32] VGPR-resident.
// Step: 16 broadcast ds_read_b128 -> 32 pk_add -> 31 pk_max tree -> fmax
// -> +em -> ds_write. Bit-exact vs reference (monotone rounding).
// ---------------------------------------------------------------------------
__global__ __launch_bounds__(64)
__attribute__((amdgpu_waves_per_eu(1, 1)))
void viterbi_fwd(
    const float* __restrict__ em, const float* __restrict__ trans,
    float* __restrict__ scoreHist, int* __restrict__ bestTag)
{
    __shared__ __align__(16) float sc_lds[TT];
    __shared__ __align__(16) float tr_lds[4096];

    const int b    = blockIdx.x;
    const int lane = threadIdx.x;
    const float* emb = em + (size_t)b * SS * TT;
    float* sh = scoreHist + (size_t)b * SS * TT;

    {
        float4* dst = (float4*)tr_lds;
        const float4* src = (const float4*)trans;
#pragma unroll
        for (int i = 0; i < 16; i++) dst[lane + i * 64] = src[lane + i * 64];
    }
    __syncthreads();

    // tpk[j] = (trans[2j][lane], trans[2j+1][lane])
    f32x2 tpk[32];
#pragma unroll
    for (int j = 0; j < 32; j++) {
        tpk[j].x = tr_lds[(2 * j) * TT + lane];
        tpk[j].y = tr_lds[(2 * j + 1) * TT + lane];
    }

    const float em0 = emb[lane];
    sc_lds[lane] = em0;
    sh[lane] = em0;   // score_0
    float sc = em0;

    float er0 = emb[1 * TT + lane];
    float er1 = emb[2 * TT + lane];
    float er2 = emb[3 * TT + lane];
    float er3 = emb[4 * TT + lane];

    float4 sq[16];
    {
        const float4* sb = (const float4*)sc_lds;
#pragma unroll
        for (int i = 0; i < 16; i++) sq[i] = sb[i];
    }

    auto step = [&](int s, float em_v) {
        const f32x2* sq2 = (const f32x2*)sq;
        f32x2 pk[32];
#pragma unroll
        for (int j = 0; j < 32; j++) pk[j] = sq2[j] + tpk[j];

#pragma unroll
        for (int m = 16; m >= 1; m >>= 1)
#pragma unroll
            for (int j = 0; j < 16; j++) {
                if (j < m) pk[j] = vmax2(pk[j], pk[j + m]);
            }
        sc = fmaxf(pk[0].x, pk[0].y) + em_v;

        sc_lds[lane] = sc;
        {
            const float4* sb = (const float4*)sc_lds;
#pragma unroll
            for (int i = 0; i < 16; i++) sq[i] = sb[i];
        }
        sh[s * TT + lane] = sc;
    };

    for (int sb = 1; sb <= 505; sb += 4) {
        step(sb + 0, er0);  er0 = emb[(sb + 4) * TT + lane];
        step(sb + 1, er1);  er1 = emb[(sb + 5) * TT + lane];
        step(sb + 2, er2);  er2 = emb[(sb + 6) * TT + lane];
        step(sb + 3, er3);  er3 = emb[((sb + 7) <= 511 ? (sb + 7) : 511) * TT + lane];
    }
    step(509, er0);
    step(510, er1);
    step(511, er2);

    float fv = sc;
    int   fa = lane;
#pragma unroll
    for (int m = 1; m <= 32; m <<= 1) {
        const float vo = __shfl_xor(fv, m, 64);
        const int   ao = __shfl_xor(fa, m, 64);
        if (vo > fv || (vo == fv && ao < fa)) { fv = vo; fa = ao; }
    }
    if (lane == 0) bestTag[b] = fa;
}

// ---------------------------------------------------------------------------
// Kernel 3: backpointer recompute (R13-validated). One wave per (b,s),
// lane = cur. Max value known bit-exact from scoreHist; first index with
// fl(fl(score+trans)+em) == sh  == numpy first-index argmax.
// ---------------------------------------------------------------------------
__global__ __launch_bounds__(256) void bp_kernel(
    const float* __restrict__ scoreHist, const float* __restrict__ em,
    const float* __restrict__ trans, unsigned char* __restrict__ hist8)
{
    __shared__ __align__(16) float tr_lds[4096];
    const int tid = threadIdx.x;
    {
        const float4* src = (const float4*)trans;
        float4* dst = (float4*)tr_lds;
        for (int i = tid; i < 1024; i += 256) dst[i] = src[i];
    }
    __syncthreads();

    const int wv   = tid >> 6;
    const int lane = tid & 63;
    const int g    = blockIdx.x * 4 + wv;
    const int b    = g / 511;
    const int s    = 1 + (g % 511);

    const f32x2* sb2 = (const f32x2*)(scoreHist + ((size_t)b * SS + (s - 1)) * TT);
    const float em_v = em[((size_t)b * SS + s) * TT + lane];
    const float sh_v = scoreHist[((size_t)b * SS + s) * TT + lane];

    f32x2 tpk[32];
#pragma unroll
    for (int j = 0; j < 32; j++) {
        tpk[j].x = tr_lds[(2 * j) * TT + lane];
        tpk[j].y = tr_lds[(2 * j + 1) * TT + lane];
    }

    f32x2 em2; em2.x = em_v; em2.y = em_v;
    f32x2 v2[32];
#pragma unroll
    for (int j = 0; j < 32; j++) {
        f32x2 cand = sb2[j] + tpk[j];
        v2[j] = cand + em2;
    }

    int idx = 63;
#pragma unroll
    for (int j = 31; j >= 0; j--) {
        idx = (v2[j].y == sh_v) ? 2 * j + 1 : idx;
        idx = (v2[j].x == sh_v) ? 2 * j     : idx;
    }

    hist8[((size_t)b * SS + s) * TT + lane] = (unsigned char)idx;
}

// ---------------------------------------------------------------------------
// Kernel 4: backtrack via readlane pointer-chase (R13-validated).
// ---------------------------------------------------------------------------
__global__ __launch_bounds__(64) void backtrack(
    const unsigned char* __restrict__ hist8, const int* __restrict__ bestTag,
    int* __restrict__ out)
{
    __shared__ int tags[SS];

    const int b    = blockIdx.x;
    const int lane = threadIdx.x;
    const unsigned char* h8 = hist8 + (size_t)b * SS * TT;

    int tag = bestTag[b];
    if (lane == 0) tags[511] = tag;

    int r0 = h8[511 * TT + lane];
    int r1 = h8[510 * TT + lane];
    int r2 = h8[509 * TT + lane];
    int r3 = h8[508 * TT + lane];

    for (int sb = 511; sb >= 11; sb -= 4) {
        tag = __builtin_amdgcn_readlane(r0, tag);
        if (lane == 0) tags[sb - 1] = tag;
        r0 = h8[(sb - 4) * TT + lane];
        tag = __builtin_amdgcn_readlane(r1, tag);
        if (lane == 0) tags[sb - 2] = tag;
        r1 = h8[(sb - 5) * TT + lane];
        tag = __builtin_amdgcn_readlane(r2, tag);
        if (lane == 0) tags[sb - 3] = tag;
        r2 = h8[(sb - 6) * TT + lane];
        tag = __builtin_amdgcn_readlane(r3, tag);
        if (lane == 0) tags[sb - 4] = tag;
        r3 = h8[(sb - 7) * TT + lane];
    }
    tag = __builtin_amdgcn_readlane(r0, tag);  if (lane == 0) tags[6] = tag;
    tag = __builtin_amdgcn_readlane(r1, tag);  if (lane == 0) tags[5] = tag;
    tag = __builtin_amdgcn_readlane(r2, tag);  if (lane == 0) tags[4] = tag;
    tag = __builtin_amdgcn_readlane(r3, tag);  if (lane == 0) tags[3] = tag;
    int q0 = h8[3 * TT + lane];
    int q1 = h8[2 * TT + lane];
    int q2 = h8[1 * TT + lane];
    tag = __builtin_amdgcn_readlane(q0, tag);  if (lane == 0) tags[2] = tag;
    tag = __builtin_amdgcn_readlane(q1, tag);  if (lane == 0) tags[1] = tag;
    tag = __builtin_amdgcn_readlane(q2, tag);  if (lane == 0) tags[0] = tag;

    __syncthreads();
#pragma unroll
    for (int s = 0; s < 8; s++)
        out[(size_t)b * SS + s * 64 + lane] = tags[s * 64 + lane];
}

// ---------------------------------------------------------------------------
extern "C" void kernel_launch(void* const* d_in, const int* in_sizes, int n_in,
                              void* d_out, int out_size, void* d_ws, size_t ws_size,
                              hipStream_t stream)
{
    const float* X     = (const float*)d_in[0];  // [64,512,768]
    const float* W     = (const float*)d_in[1];  // [64,768]
    const float* bias  = (const float*)d_in[2];  // [64]
    const float* trans = (const float*)d_in[3];  // [64,64]
    int* out = (int*)d_out;                      // [64,512] int32

    char* ws = (char*)d_ws;
    float*         em        = (float*)ws;                      // 8,388,608 B
    float*         scoreHist = (float*)(ws + 8388608);          // 8,388,608 B
    unsigned char* hist8     = (unsigned char*)(ws + 16777216); // 2,097,152 B
    int*           bestTag   = (int*)(ws + 18874368);           // 256 B
    float*         WT        = (float*)(ws + 18874624);         // 196,608 B

    transpose_w<<<dim3(192), dim3(256), 0, stream>>>(W, WT);
    emis_gemm<<<dim3(512), dim3(256), 0, stream>>>(X, WT, bias, em);
    viterbi_fwd<<<dim3(64), dim3(64), 0, stream>>>(em, trans, scoreHist, bestTag);
    bp_kernel<<<dim3(8176), dim3(256), 0, stream>>>(scoreHist, em, trans, hist8);
    backtrack<<<dim3(64), dim3(64), 0, stream>>>(hist8, bestTag, out);
}

// Round 19
// 226.590 us; speedup vs baseline: 1.6400x; 1.6400x over previous
//
#include <hip/hip_runtime.h>

#define SS 512
#define DD 768
#define TT 64

typedef __attribute__((ext_vector_type(2))) float f32x2;

__device__ __forceinline__ f32x2 vmax2(f32x2 a, f32x2 b) {
    return __builtin_elementwise_max(a, b);
}

// ---------------------------------------------------------------------------
// Kernel 1: emissions GEMM (R13-validated 64x64 config, grid 512).
// ---------------------------------------------------------------------------
__global__ __launch_bounds__(256) void emis_gemm(
    const float* __restrict__ X, const float* __restrict__ W,
    const float* __restrict__ bias, float* __restrict__ em)
{
    __shared__ __align__(16) float Xs[16][68];
    __shared__ __align__(16) float Ws[16][68];

    const int tid = threadIdx.x;
    const int m0  = blockIdx.x * 64;
    const int tm  = tid >> 4;
    const int tn  = tid & 15;
    const int lr  = tid >> 2;
    const int lk  = tid & 3;

    float acc[4][4];
#pragma unroll
    for (int i = 0; i < 4; i++)
#pragma unroll
        for (int j = 0; j < 4; j++) acc[i][j] = 0.f;

    float4 xr, wr;
    xr = *(const float4*)&X[(size_t)(m0 + lr) * DD + lk * 4];
    wr = *(const float4*)&W[(size_t)lr * DD + lk * 4];

    for (int t = 0; t < 48; t++) {
        Xs[lk * 4 + 0][lr] = xr.x;  Xs[lk * 4 + 1][lr] = xr.y;
        Xs[lk * 4 + 2][lr] = xr.z;  Xs[lk * 4 + 3][lr] = xr.w;
        Ws[lk * 4 + 0][lr] = wr.x;  Ws[lk * 4 + 1][lr] = wr.y;
        Ws[lk * 4 + 2][lr] = wr.z;  Ws[lk * 4 + 3][lr] = wr.w;
        __syncthreads();

        if (t < 47) {
            const int k0 = (t + 1) * 16;
            xr = *(const float4*)&X[(size_t)(m0 + lr) * DD + k0 + lk * 4];
            wr = *(const float4*)&W[(size_t)lr * DD + k0 + lk * 4];
        }

#pragma unroll
        for (int k = 0; k < 16; k++) {
            float a[4], bv[4];
            *(float4*)&a[0]  = *(const float4*)&Xs[k][tm * 4];
            *(float4*)&bv[0] = *(const float4*)&Ws[k][tn * 4];
#pragma unroll
            for (int i = 0; i < 4; i++)
#pragma unroll
                for (int j = 0; j < 4; j++)
                    acc[i][j] = fmaf(a[i], bv[j], acc[i][j]);
        }
        __syncthreads();
    }

    const float4 bv4 = *(const float4*)&bias[tn * 4];
#pragma unroll
    for (int i = 0; i < 4; i++) {
        const size_t row = (size_t)(m0 + tm * 4 + i);
        float4 o;
        o.x = acc[i][0] + bv4.x;  o.y = acc[i][1] + bv4.y;
        o.z = acc[i][2] + bv4.z;  o.w = acc[i][3] + bv4.w;
        *(float4*)&em[row * TT + tn * 4] = o;
    }
}

// ---------------------------------------------------------------------------
// Kernel 2: Viterbi forward, VALUE ONLY (R10 code, 112 us measured).
// One wave per batch, waves_per_eu(1,1) keeps tpk[32] VGPR-resident.
// Step: 16 broadcast ds_read_b128 -> 32 pk_add -> 31 pk_max tree -> fmax
// -> +em -> ds_write. Bit-exact vs reference (monotone rounding).
// ---------------------------------------------------------------------------
__global__ __launch_bounds__(64)
__attribute__((amdgpu_waves_per_eu(1, 1)))
void viterbi_fwd(
    const float* __restrict__ em, const float* __restrict__ trans,
    float* __restrict__ scoreHist, int* __restrict__ bestTag)
{
    __shared__ __align__(16) float sc_lds[TT];
    __shared__ __align__(16) float tr_lds[4096];

    const int b    = blockIdx.x;
    const int lane = threadIdx.x;
    const float* emb = em + (size_t)b * SS * TT;
    float* sh = scoreHist + (size_t)b * SS * TT;

    {
        float4* dst = (float4*)tr_lds;
        const float4* src = (const float4*)trans;
#pragma unroll
        for (int i = 0; i < 16; i++) dst[lane + i * 64] = src[lane + i * 64];
    }
    __syncthreads();

    // tpk[j] = (trans[2j][lane], trans[2j+1][lane])
    f32x2 tpk[32];
#pragma unroll
    for (int j = 0; j < 32; j++) {
        tpk[j].x = tr_lds[(2 * j) * TT + lane];
        tpk[j].y = tr_lds[(2 * j + 1) * TT + lane];
    }

    const float em0 = emb[lane];
    sc_lds[lane] = em0;
    sh[lane] = em0;   // score_0
    float sc = em0;

    float er0 = emb[1 * TT + lane];
    float er1 = emb[2 * TT + lane];
    float er2 = emb[3 * TT + lane];
    float er3 = emb[4 * TT + lane];

    float4 sq[16];
    {
        const float4* sb = (const float4*)sc_lds;
#pragma unroll
        for (int i = 0; i < 16; i++) sq[i] = sb[i];
    }

    auto step = [&](int s, float em_v) {
        const f32x2* sq2 = (const f32x2*)sq;
        f32x2 pk[32];
#pragma unroll
        for (int j = 0; j < 32; j++) pk[j] = sq2[j] + tpk[j];

#pragma unroll
        for (int m = 16; m >= 1; m >>= 1)
#pragma unroll
            for (int j = 0; j < 16; j++) {
                if (j < m) pk[j] = vmax2(pk[j], pk[j + m]);
            }
        sc = fmaxf(pk[0].x, pk[0].y) + em_v;

        sc_lds[lane] = sc;
        {
            const float4* sb = (const float4*)sc_lds;
#pragma unroll
            for (int i = 0; i < 16; i++) sq[i] = sb[i];
        }
        sh[s * TT + lane] = sc;
    };

    for (int sb = 1; sb <= 505; sb += 4) {
        step(sb + 0, er0);  er0 = emb[(sb + 4) * TT + lane];
        step(sb + 1, er1);  er1 = emb[(sb + 5) * TT + lane];
        step(sb + 2, er2);  er2 = emb[(sb + 6) * TT + lane];
        step(sb + 3, er3);  er3 = emb[((sb + 7) <= 511 ? (sb + 7) : 511) * TT + lane];
    }
    step(509, er0);
    step(510, er1);
    step(511, er2);

    float fv = sc;
    int   fa = lane;
#pragma unroll
    for (int m = 1; m <= 32; m <<= 1) {
        const float vo = __shfl_xor(fv, m, 64);
        const int   ao = __shfl_xor(fa, m, 64);
        if (vo > fv || (vo == fv && ao < fa)) { fv = vo; fa = ao; }
    }
    if (lane == 0) bestTag[b] = fa;
}

// ---------------------------------------------------------------------------
// Kernel 3: backpointer recompute, 4 STEPS PER WAVE (amortizes the 64-DS-read
// tpk gather + trans staging + barrier over 4 equality-scans).
// Wave g: b = g>>7, steps s = 1+4*(g&127) + {0..3} (s<=511 guarded).
// Math per step identical to R13-validated equality scan: max value known
// bit-exact from scoreHist; first index with fl(fl(score+trans)+em) == sh.
// ---------------------------------------------------------------------------
__global__ __launch_bounds__(256) void bp_kernel(
    const float* __restrict__ scoreHist, const float* __restrict__ em,
    const float* __restrict__ trans, unsigned char* __restrict__ hist8)
{
    __shared__ __align__(16) float tr_lds[4096];
    const int tid = threadIdx.x;
    {
        const float4* src = (const float4*)trans;
        float4* dst = (float4*)tr_lds;
        for (int i = tid; i < 1024; i += 256) dst[i] = src[i];
    }
    __syncthreads();

    const int wv   = tid >> 6;
    const int lane = tid & 63;
    const int g    = blockIdx.x * 4 + wv;   // 0..8191
    const int b    = g >> 7;                // 0..63
    const int s0   = 1 + (g & 127) * 4;     // 1,5,...,509

    // tpk[j] = (trans[2j][lane], trans[2j+1][lane]) -- loaded ONCE per wave
    f32x2 tpk[32];
#pragma unroll
    for (int j = 0; j < 32; j++) {
        tpk[j].x = tr_lds[(2 * j) * TT + lane];
        tpk[j].y = tr_lds[(2 * j + 1) * TT + lane];
    }

    for (int i = 0; i < 4; i++) {
        const int s = s0 + i;
        if (s > 511) break;

        const f32x2* sb2 = (const f32x2*)(scoreHist + ((size_t)b * SS + (s - 1)) * TT);
        const float em_v = em[((size_t)b * SS + s) * TT + lane];
        const float sh_v = scoreHist[((size_t)b * SS + s) * TT + lane];

        f32x2 em2; em2.x = em_v; em2.y = em_v;
        f32x2 v2[32];
#pragma unroll
        for (int j = 0; j < 32; j++) {
            f32x2 cand = sb2[j] + tpk[j];
            v2[j] = cand + em2;
        }

        int idx = 63;
#pragma unroll
        for (int j = 31; j >= 0; j--) {
            idx = (v2[j].y == sh_v) ? 2 * j + 1 : idx;
            idx = (v2[j].x == sh_v) ? 2 * j     : idx;
        }

        hist8[((size_t)b * SS + s) * TT + lane] = (unsigned char)idx;
    }
}

// ---------------------------------------------------------------------------
// Kernel 4: backtrack via readlane pointer-chase (R13-validated).
// ---------------------------------------------------------------------------
__global__ __launch_bounds__(64) void backtrack(
    const unsigned char* __restrict__ hist8, const int* __restrict__ bestTag,
    int* __restrict__ out)
{
    __shared__ int tags[SS];

    const int b    = blockIdx.x;
    const int lane = threadIdx.x;
    const unsigned char* h8 = hist8 + (size_t)b * SS * TT;

    int tag = bestTag[b];
    if (lane == 0) tags[511] = tag;

    int r0 = h8[511 * TT + lane];
    int r1 = h8[510 * TT + lane];
    int r2 = h8[509 * TT + lane];
    int r3 = h8[508 * TT + lane];

    for (int sb = 511; sb >= 11; sb -= 4) {
        tag = __builtin_amdgcn_readlane(r0, tag);
        if (lane == 0) tags[sb - 1] = tag;
        r0 = h8[(sb - 4) * TT + lane];
        tag = __builtin_amdgcn_readlane(r1, tag);
        if (lane == 0) tags[sb - 2] = tag;
        r1 = h8[(sb - 5) * TT + lane];
        tag = __builtin_amdgcn_readlane(r2, tag);
        if (lane == 0) tags[sb - 3] = tag;
        r2 = h8[(sb - 6) * TT + lane];
        tag = __builtin_amdgcn_readlane(r3, tag);
        if (lane == 0) tags[sb - 4] = tag;
        r3 = h8[(sb - 7) * TT + lane];
    }
    tag = __builtin_amdgcn_readlane(r0, tag);  if (lane == 0) tags[6] = tag;
    tag = __builtin_amdgcn_readlane(r1, tag);  if (lane == 0) tags[5] = tag;
    tag = __builtin_amdgcn_readlane(r2, tag);  if (lane == 0) tags[4] = tag;
    tag = __builtin_amdgcn_readlane(r3, tag);  if (lane == 0) tags[3] = tag;
    int q0 = h8[3 * TT + lane];
    int q1 = h8[2 * TT + lane];
    int q2 = h8[1 * TT + lane];
    tag = __builtin_amdgcn_readlane(q0, tag);  if (lane == 0) tags[2] = tag;
    tag = __builtin_amdgcn_readlane(q1, tag);  if (lane == 0) tags[1] = tag;
    tag = __builtin_amdgcn_readlane(q2, tag);  if (lane == 0) tags[0] = tag;

    __syncthreads();
#pragma unroll
    for (int s = 0; s < 8; s++)
        out[(size_t)b * SS + s * 64 + lane] = tags[s * 64 + lane];
}

// ---------------------------------------------------------------------------
extern "C" void kernel_launch(void* const* d_in, const int* in_sizes, int n_in,
                              void* d_out, int out_size, void* d_ws, size_t ws_size,
                              hipStream_t stream)
{
    const float* X     = (const float*)d_in[0];  // [64,512,768]
    const float* W     = (const float*)d_in[1];  // [64,768]
    const float* bias  = (const float*)d_in[2];  // [64]
    const float* trans = (const float*)d_in[3];  // [64,64]
    int* out = (int*)d_out;                      // [64,512] int32

    char* ws = (char*)d_ws;
    float*         em        = (float*)ws;                      // 8,388,608 B
    float*         scoreHist = (float*)(ws + 8388608);          // 8,388,608 B
    unsigned char* hist8     = (unsigned char*)(ws + 16777216); // 2,097,152 B
    int*           bestTag   = (int*)(ws + 18874368);           // 256 B

    emis_gemm<<<dim3(512), dim3(256), 0, stream>>>(X, W, bias, em);
    viterbi_fwd<<<dim3(64), dim3(64), 0, stream>>>(em, trans, scoreHist, bestTag);
    bp_kernel<<<dim3(2048), dim3(256), 0, stream>>>(scoreHist, em, trans, hist8);
    backtrack<<<dim3(64), dim3(64), 0, stream>>>(hist8, bestTag, out);
}